// Round 4
// baseline (241.998 us; speedup 1.0000x reference)
//
#include <hip/hip_runtime.h>

// Sparsemax, d=1024, 32768 rows, fp32 — TWO-PASS split.
// R0-R3 post-mortem: four different fused schedules all land at 78-84us
// with HBM ~31% and VALU ~27%. The fused shape forces every wave through
// load-burst -> long register solve (no memory issued) -> store-burst,
// and the compiler twice refused to keep a 2-deep register pipeline
// alive (VGPR_Count=32 both times). Splitting the phases into two
// kernels makes the overlap the hardware's job:
//   K1: per-row tau solve, READ-ONLY (writes 4B/row into d_ws).
//   K2: p = relu(z - tau[row]) — a pure triad stream, same structure as
//       the 6.3TB/s float4 copy; z is L3-warm from K1 (134MB < 256MB L3).
// Newton iteration t' = t + (sum(relu(z-t)) - 1)/#{z>t} from t0=max-1 is
// monotone from below on the convex piecewise-linear objective (~4-8
// iters). rcp instead of divide: n is an exact small int, ~2^-22 rel
// err, final step -> 0, tau err ~1e-7 << 2e-3 tolerance.

#define ROW_D 1024

typedef float f4 __attribute__((ext_vector_type(4)));

template <int CTRL, int RMASK>
__device__ __forceinline__ float dpp_mv(float x) {
    return __builtin_bit_cast(float, __builtin_amdgcn_update_dpp(
        __builtin_bit_cast(int, x), __builtin_bit_cast(int, x),
        CTRL, RMASK, 0xf, false));
}

__device__ __forceinline__ float dpp_sum_to63(float x) {
    x += dpp_mv<0x111, 0xf>(x);   // row_shr:1
    x += dpp_mv<0x112, 0xf>(x);   // row_shr:2
    x += dpp_mv<0x114, 0xf>(x);   // row_shr:4
    x += dpp_mv<0x118, 0xf>(x);   // row_shr:8
    x += dpp_mv<0x142, 0xa>(x);   // row_bcast15 -> rows 1,3
    x += dpp_mv<0x143, 0xc>(x);   // row_bcast31 -> rows 2,3
    return x;
}
__device__ __forceinline__ float dpp_max_to63(float x) {
    x = fmaxf(x, dpp_mv<0x111, 0xf>(x));
    x = fmaxf(x, dpp_mv<0x112, 0xf>(x));
    x = fmaxf(x, dpp_mv<0x114, 0xf>(x));
    x = fmaxf(x, dpp_mv<0x118, 0xf>(x));
    x = fmaxf(x, dpp_mv<0x142, 0xa>(x));
    x = fmaxf(x, dpp_mv<0x143, 0xc>(x));
    return x;
}
__device__ __forceinline__ float bcast63(float x) {
    return __builtin_bit_cast(float,
        __builtin_amdgcn_readlane(__builtin_bit_cast(int, x), 63));
}
__device__ __forceinline__ float fast_rcp(float x) {
    float r;
    asm("v_rcp_f32 %0, %1" : "=v"(r) : "v"(x));
    return r;
}

// ---------- K1: tau per row (read-only pass) ----------
__global__ __launch_bounds__(256) void tau_kernel(
    const float* __restrict__ z, float* __restrict__ tau, int nrows) {
    const int lane = (int)(threadIdx.x & 63u);
    const int row  = (int)(blockIdx.x << 2) + (int)(threadIdx.x >> 6);
    if (row >= nrows) return;

    const f4* __restrict__ zin = reinterpret_cast<const f4*>(z + (size_t)row * ROW_D);
    f4 v[4];
#pragma unroll
    for (int j = 0; j < 4; ++j) v[j] = zin[lane + 64 * j];

    float mj[4];
#pragma unroll
    for (int j = 0; j < 4; ++j)
        mj[j] = fmaxf(fmaxf(v[j].x, v[j].y), fmaxf(v[j].z, v[j].w));
    float m = fmaxf(fmaxf(mj[0], mj[1]), fmaxf(mj[2], mj[3]));
    m = bcast63(dpp_max_to63(m));

    float t = m - 1.0f;
#pragma unroll 1
    for (int it = 0; it < 16; ++it) {
        float sj[4];
        int n = 0;
#pragma unroll
        for (int j = 0; j < 4; ++j) {
            const float d0 = v[j].x - t, d1 = v[j].y - t;
            const float d2 = v[j].z - t, d3 = v[j].w - t;
            sj[j] = (fmaxf(d0, 0.0f) + fmaxf(d1, 0.0f)) +
                    (fmaxf(d2, 0.0f) + fmaxf(d3, 0.0f));
            n += __popcll(__ballot(d0 > 0.0f));
            n += __popcll(__ballot(d1 > 0.0f));
            n += __popcll(__ballot(d2 > 0.0f));
            n += __popcll(__ballot(d3 > 0.0f));
        }
        const float S = bcast63(dpp_sum_to63((sj[0] + sj[1]) + (sj[2] + sj[3])));
        const float step = (S - 1.0f) * fast_rcp((float)n);   // n >= 1 always
        t += step;
        if (step <= 1e-6f) break;   // wave-uniform exit
    }
    if (lane == 0) tau[row] = t;
}

// ---------- K2: p = relu(z - tau[row]) — pure stream ----------
__global__ __launch_bounds__(256) void apply_kernel(
    const float* __restrict__ z, const float* __restrict__ tau,
    float* __restrict__ out, int n4) {
    int i = (int)(blockIdx.x * blockDim.x + threadIdx.x);
    const int stride = (int)(gridDim.x * blockDim.x);
    const f4* __restrict__ zi = reinterpret_cast<const f4*>(z);
    f4* __restrict__ po = reinterpret_cast<f4*>(out);
    for (; i < n4; i += stride) {
        const f4 v = zi[i];
        const float t = tau[i >> 8];          // ROW_D/4 = 256 f4 per row
        f4 o;
        o.x = fmaxf(v.x - t, 0.0f);
        o.y = fmaxf(v.y - t, 0.0f);
        o.z = fmaxf(v.z - t, 0.0f);
        o.w = fmaxf(v.w - t, 0.0f);
        po[i] = o;
    }
}

// ---------- fallback (fused R0 kernel) if workspace is too small ----------
__global__ __launch_bounds__(256) void sparsemax_fused(
    const float* __restrict__ z, float* __restrict__ out, int nrows) {
    const int lane = (int)(threadIdx.x & 63u);
    const int row  = (int)(blockIdx.x << 2) + (int)(threadIdx.x >> 6);
    if (row >= nrows) return;
    const f4* __restrict__ zin = reinterpret_cast<const f4*>(z + (size_t)row * ROW_D);
    f4* __restrict__ pout      = reinterpret_cast<f4*>(out + (size_t)row * ROW_D);
    f4 v[4];
#pragma unroll
    for (int j = 0; j < 4; ++j) v[j] = zin[lane + 64 * j];
    float mj[4];
#pragma unroll
    for (int j = 0; j < 4; ++j)
        mj[j] = fmaxf(fmaxf(v[j].x, v[j].y), fmaxf(v[j].z, v[j].w));
    float m = fmaxf(fmaxf(mj[0], mj[1]), fmaxf(mj[2], mj[3]));
    m = bcast63(dpp_max_to63(m));
    float t = m - 1.0f;
#pragma unroll 1
    for (int it = 0; it < 16; ++it) {
        float sj[4];
        int n = 0;
#pragma unroll
        for (int j = 0; j < 4; ++j) {
            const float d0 = v[j].x - t, d1 = v[j].y - t;
            const float d2 = v[j].z - t, d3 = v[j].w - t;
            sj[j] = (fmaxf(d0, 0.0f) + fmaxf(d1, 0.0f)) +
                    (fmaxf(d2, 0.0f) + fmaxf(d3, 0.0f));
            n += __popcll(__ballot(d0 > 0.0f));
            n += __popcll(__ballot(d1 > 0.0f));
            n += __popcll(__ballot(d2 > 0.0f));
            n += __popcll(__ballot(d3 > 0.0f));
        }
        const float S = bcast63(dpp_sum_to63((sj[0] + sj[1]) + (sj[2] + sj[3])));
        const float step = (S - 1.0f) * fast_rcp((float)n);
        t += step;
        if (step <= 1e-6f) break;
    }
#pragma unroll
    for (int j = 0; j < 4; ++j) {
        f4 o;
        o.x = fmaxf(v[j].x - t, 0.0f);
        o.y = fmaxf(v[j].y - t, 0.0f);
        o.z = fmaxf(v[j].z - t, 0.0f);
        o.w = fmaxf(v[j].w - t, 0.0f);
        pout[lane + 64 * j] = o;
    }
}

extern "C" void kernel_launch(void* const* d_in, const int* in_sizes, int n_in,
                              void* d_out, int out_size, void* d_ws, size_t ws_size,
                              hipStream_t stream) {
    const float* z = (const float*)d_in[0];
    float* out = (float*)d_out;
    const int n = in_sizes[0];            // 8*4096*1024
    const int nrows = n / ROW_D;          // 32768

    if (d_ws != nullptr && ws_size >= (size_t)nrows * sizeof(float)) {
        float* tau = (float*)d_ws;
        const int blocks1 = (nrows + 3) / 4;            // 1 wave per row
        tau_kernel<<<blocks1, 256, 0, stream>>>(z, tau, nrows);
        const int n4 = n / 4;
        apply_kernel<<<2048, 256, 0, stream>>>(z, tau, out, n4);
    } else {
        const int blocks = (nrows + 3) / 4;
        sparsemax_fused<<<blocks, 256, 0, stream>>>(z, out, nrows);
    }
}

// Round 5
// 232.847 us; speedup vs baseline: 1.0393x; 1.0393x over previous
//
#include <hip/hip_runtime.h>

// Sparsemax, d=1024, 32768 rows, fp32 — fused, LDS-DMA software pipeline.
// R0-R4 post-mortem: every schedule lands ~80us at HBM 31% / VALU 27%
// (anti-phased). Wave lifetime ~50k cycles for ~600 insts + 4KB loads:
// the convoy -- each wave issues 4KB in ~8 cycles then goes memory-silent
// for the whole solve. Two register-prefetch attempts were KILLED by the
// compiler (VGPR_Count=32 both times: second buffer never live).
// Fix: prefetch the next row via __builtin_amdgcn_global_load_lds DMA
// into a per-wave LDS double buffer. The DMA consumes no VGPRs (regalloc
// can't sink it), is side-effecting + fenced by sched_barrier(0)
// (scheduler can't move it), and the solve has no vmcnt-dependent uses
// (SIInsertWaitcnts won't drain it). So the 4KB read for row r+W is
// genuinely in flight during the entire solve of row r.
// Solve: Newton t' = t + (sum(relu(z-t)) - 1)/#{z>t} from t0 = max-1,
// monotone from below on the convex piecewise-linear objective (~6-8
// iters). Support count as FLOAT via cndmask + a second independent DPP
// tree (replaces 16 ballot->popcount VALU->SALU interlock chains/iter).
// rcp not divide: count is an exact small int, ~2^-22 rel err, final
// Newton step -> 0, tau err ~1e-7 << 2e-3 tolerance.

#define ROW_D 1024

typedef float f4 __attribute__((ext_vector_type(4)));

template <int CTRL, int RMASK>
__device__ __forceinline__ float dpp_mv(float x) {
    return __builtin_bit_cast(float, __builtin_amdgcn_update_dpp(
        __builtin_bit_cast(int, x), __builtin_bit_cast(int, x),
        CTRL, RMASK, 0xf, false));
}

// Wave64 sum -> total lands in lane 63. row_shr:k folds each 16-lane row
// into its top lane; bcast15/31 fold rows.
__device__ __forceinline__ float dpp_sum_to63(float x) {
    x += dpp_mv<0x111, 0xf>(x);   // row_shr:1
    x += dpp_mv<0x112, 0xf>(x);   // row_shr:2
    x += dpp_mv<0x114, 0xf>(x);   // row_shr:4
    x += dpp_mv<0x118, 0xf>(x);   // row_shr:8
    x += dpp_mv<0x142, 0xa>(x);   // row_bcast15 -> rows 1,3
    x += dpp_mv<0x143, 0xc>(x);   // row_bcast31 -> rows 2,3
    return x;
}
__device__ __forceinline__ float dpp_max_to63(float x) {
    x = fmaxf(x, dpp_mv<0x111, 0xf>(x));
    x = fmaxf(x, dpp_mv<0x112, 0xf>(x));
    x = fmaxf(x, dpp_mv<0x114, 0xf>(x));
    x = fmaxf(x, dpp_mv<0x118, 0xf>(x));
    x = fmaxf(x, dpp_mv<0x142, 0xa>(x));
    x = fmaxf(x, dpp_mv<0x143, 0xc>(x));
    return x;
}
__device__ __forceinline__ float bcast63(float x) {
    return __builtin_bit_cast(float,
        __builtin_amdgcn_readlane(__builtin_bit_cast(int, x), 63));
}
__device__ __forceinline__ float fast_rcp(float x) {
    float r;
    asm("v_rcp_f32 %0, %1" : "=v"(r) : "v"(x));
    return r;
}

// DMA one 4KB row into this wave's LDS slot: 4 x (64 lanes x 16B) insts.
// Global src is per-lane; LDS dst is wave-uniform base + lane*16.
__device__ __forceinline__ void prefetch_row(const float* __restrict__ z,
                                             int row, int lane,
                                             float* ldsbase) {
    const char* g = (const char*)(z + (size_t)row * ROW_D) + (size_t)lane * 16;
#pragma unroll
    for (int j = 0; j < 4; ++j) {
        __builtin_amdgcn_global_load_lds(
            (const __attribute__((address_space(1))) void*)(g + j * 1024),
            (__attribute__((address_space(3))) void*)(ldsbase + j * 256),
            16, 0, 0);
    }
}

__device__ __forceinline__ float solve_tau(const f4 (&v)[4]) {
    // Row max: pairwise reg tree, then DPP wave-max.
    float mj[4];
#pragma unroll
    for (int j = 0; j < 4; ++j)
        mj[j] = fmaxf(fmaxf(v[j].x, v[j].y), fmaxf(v[j].z, v[j].w));
    float m = fmaxf(fmaxf(mj[0], mj[1]), fmaxf(mj[2], mj[3]));
    m = bcast63(dpp_max_to63(m));

    float t = m - 1.0f;
#pragma unroll 1
    for (int it = 0; it < 16; ++it) {
        float sj[4], cj[4];
#pragma unroll
        for (int j = 0; j < 4; ++j) {
            const float d0 = v[j].x - t, d1 = v[j].y - t;
            const float d2 = v[j].z - t, d3 = v[j].w - t;
            sj[j] = (fmaxf(d0, 0.0f) + fmaxf(d1, 0.0f)) +
                    (fmaxf(d2, 0.0f) + fmaxf(d3, 0.0f));
            cj[j] = ((d0 > 0.0f ? 1.0f : 0.0f) + (d1 > 0.0f ? 1.0f : 0.0f)) +
                    ((d2 > 0.0f ? 1.0f : 0.0f) + (d3 > 0.0f ? 1.0f : 0.0f));
        }
        // Two independent DPP trees (S and count) interleave in the SIMD.
        const float S = bcast63(dpp_sum_to63((sj[0] + sj[1]) + (sj[2] + sj[3])));
        const float C = bcast63(dpp_sum_to63((cj[0] + cj[1]) + (cj[2] + cj[3])));
        // C >= 1 always (t stays strictly below max).
        const float step = (S - 1.0f) * fast_rcp(C);
        t += step;
        if (step <= 1e-6f) break;   // wave-uniform exit
    }
    return t;
}

__device__ __forceinline__ void store_row(const f4 (&v)[4], float t,
                                          float* __restrict__ out,
                                          int row, int lane) {
    f4* __restrict__ p = reinterpret_cast<f4*>(out + (size_t)row * ROW_D);
#pragma unroll
    for (int j = 0; j < 4; ++j) {
        f4 o;
        o.x = fmaxf(v[j].x - t, 0.0f);
        o.y = fmaxf(v[j].y - t, 0.0f);
        o.z = fmaxf(v[j].z - t, 0.0f);
        o.w = fmaxf(v[j].w - t, 0.0f);
        p[lane + 64 * j] = o;
    }
}

__global__ __launch_bounds__(256) void sparsemax_kernel(
    const float* __restrict__ z, float* __restrict__ out, int nrows) {
    const int lane = (int)(threadIdx.x & 63u);
    const int w    = (int)(threadIdx.x >> 6);          // wave id in block
    int r = (int)(blockIdx.x << 2) + w;
    const int W = (int)(gridDim.x << 2);               // row stride per stage
    if (r >= nrows) return;

    // Per-wave LDS double buffer: 2 x 4KB. 32KB/block -> 5 blocks/CU.
    __shared__ float lds[4][2][ROW_D];

    // Prologue: row r straight to registers; DMA row r+W into slot 0.
    f4 v[4];
    const f4* __restrict__ zin = reinterpret_cast<const f4*>(z + (size_t)r * ROW_D);
#pragma unroll
    for (int j = 0; j < 4; ++j) v[j] = zin[lane + 64 * j];

    int rn = r + W;
    int s = 0;
    if (rn < nrows) prefetch_row(z, rn, lane, &lds[w][0][0]);
    __builtin_amdgcn_sched_barrier(0);

    for (;;) {
        const float t = solve_tau(v);      // DMA for row rn in flight here
        store_row(v, t, out, r, lane);
        if (rn >= nrows) break;

        // Drain DMA (and our stores), pull row rn from LDS into regs.
        asm volatile("s_waitcnt vmcnt(0)" ::: "memory");
        __builtin_amdgcn_sched_barrier(0);
        const f4* lsrc = reinterpret_cast<const f4*>(&lds[w][s][0]);
#pragma unroll
        for (int j = 0; j < 4; ++j) v[j] = lsrc[lane + 64 * j];

        const int nn = rn + W;
        if (nn < nrows) prefetch_row(z, nn, lane, &lds[w][s ^ 1][0]);
        __builtin_amdgcn_sched_barrier(0);  // pin DMA above next solve
        r = rn; rn = nn; s ^= 1;
    }
}

extern "C" void kernel_launch(void* const* d_in, const int* in_sizes, int n_in,
                              void* d_out, int out_size, void* d_ws, size_t ws_size,
                              hipStream_t stream) {
    const float* z = (const float*)d_in[0];
    float* out = (float*)d_out;
    const int n = in_sizes[0];            // 8*4096*1024
    const int nrows = n / ROW_D;          // 32768
    // 2048 blocks x 4 waves = 8192 wave-slots; each wave pipelines
    // nrows/8192 = 4 rows (stride W = 8192 rows).
    int blocks = 2048;
    const int max_blocks = (nrows + 3) >> 2;
    if (blocks > max_blocks) blocks = max_blocks;
    sparsemax_kernel<<<blocks, 256, 0, stream>>>(z, out, nrows);
}

// Round 6
// 226.007 us; speedup vs baseline: 1.0708x; 1.0303x over previous
//
#include <hip/hip_runtime.h>

// Sparsemax, d=1024, 32768 rows, fp32 — top-4 compacted Newton solve.
// R0-R5 record: six schedules (1-row, 2-row ILP, persistent, sched_barrier,
// two-pass, LDS-DMA pipeline) ALL land at 78-84us, HBM ~31%, VALU 27-36%.
// R5 proved load latency is irrelevant (HW-enforced prefetch: zero gain).
// Budget: 1500 CU-cycles/row measured vs ~425 of VALU issue = 28% == the
// measured VALUBusy. Surviving model: time ~ VALU work x ~3x stall
// dilation. So this round cuts the WORK: with t0 = max-1 and t monotone
// increasing, only elements > max-1 ever contribute to S(t) or C(t)
// (~11/1024 for this data). Per lane, top-4-of-16 via a one-time sorting
// network (~85 VALU); Newton then evaluates 4 elements/lane/iter instead
// of 16 (one DPP tree + SALU ballot counts, ~26 VALU/iter vs ~112).
// EXACT: if any lane's 4th-largest > max-1 (wave ballot; ~1e-2 of rows
// for Gaussian data), that wave runs the full 16-element loop instead.
// Newton t' = t + (S(t)-1)/C(t) from t0=max-1 is monotone from below on
// the convex piecewise-linear objective; identical trajectory in both
// paths. rcp not divide (C is an exact small int; ~2^-22 rel err,
// final step -> 0, tau err ~1e-7 << 2e-3 tolerance).

#define ROW_D 1024

typedef float f4 __attribute__((ext_vector_type(4)));

template <int CTRL, int RMASK>
__device__ __forceinline__ float dpp_mv(float x) {
    return __builtin_bit_cast(float, __builtin_amdgcn_update_dpp(
        __builtin_bit_cast(int, x), __builtin_bit_cast(int, x),
        CTRL, RMASK, 0xf, false));
}

// Wave64 sum -> total lands in lane 63. row_shr:k folds each 16-lane row
// into its top lane; bcast15/31 fold rows.
__device__ __forceinline__ float dpp_sum_to63(float x) {
    x += dpp_mv<0x111, 0xf>(x);   // row_shr:1
    x += dpp_mv<0x112, 0xf>(x);   // row_shr:2
    x += dpp_mv<0x114, 0xf>(x);   // row_shr:4
    x += dpp_mv<0x118, 0xf>(x);   // row_shr:8
    x += dpp_mv<0x142, 0xa>(x);   // row_bcast15 -> rows 1,3
    x += dpp_mv<0x143, 0xc>(x);   // row_bcast31 -> rows 2,3
    return x;
}
__device__ __forceinline__ float dpp_max_to63(float x) {
    x = fmaxf(x, dpp_mv<0x111, 0xf>(x));
    x = fmaxf(x, dpp_mv<0x112, 0xf>(x));
    x = fmaxf(x, dpp_mv<0x114, 0xf>(x));
    x = fmaxf(x, dpp_mv<0x118, 0xf>(x));
    x = fmaxf(x, dpp_mv<0x142, 0xa>(x));
    x = fmaxf(x, dpp_mv<0x143, 0xc>(x));
    return x;
}
__device__ __forceinline__ float bcast63(float x) {
    return __builtin_bit_cast(float,
        __builtin_amdgcn_readlane(__builtin_bit_cast(int, x), 63));
}
__device__ __forceinline__ float fast_rcp(float x) {
    float r;
    asm("v_rcp_f32 %0, %1" : "=v"(r) : "v"(x));
    return r;
}

// Compare-exchange, descending (a keeps max).
__device__ __forceinline__ void ce(float& a, float& b) {
    const float hi = fmaxf(a, b);
    const float lo = fminf(a, b);
    a = hi; b = lo;
}
// Sort 4 desc: 5 CE.
__device__ __forceinline__ void sort4(float& a, float& b, float& c, float& d) {
    ce(a, b); ce(c, d); ce(a, c); ce(b, d); ce(b, c);
}
// Top-4 of two desc-sorted 4-lists (pruned Batcher odd-even merge, 15 VALU).
__device__ __forceinline__ void merge44_top4(
    float A0, float A1, float A2, float A3,
    float B0, float B1, float B2, float B3,
    float& R0, float& R1, float& R2, float& R3) {
    float e0 = A0, e1 = A2, e2 = B0, e3 = B2;
    ce(e0, e2); ce(e1, e3); ce(e1, e2);          // E = (e0,e1,e2,.)
    float o0 = A1, o1 = A3, o2 = B1, o3 = B3;
    ce(o0, o2); ce(o1, o3); ce(o1, o2);          // O = (o0,o1,.)
    R0 = e0;
    float x = o0, y = e1;
    ce(x, y);
    R1 = x; R2 = y;
    R3 = fmaxf(o1, e2);
}

__global__ __launch_bounds__(256) void sparsemax_kernel(
    const float* __restrict__ z, float* __restrict__ out, int nrows) {
    const int lane = (int)(threadIdx.x & 63u);
    const int row  = (int)(blockIdx.x << 2) + (int)(threadIdx.x >> 6);
    if (row >= nrows) return;

    const f4* __restrict__ zin = reinterpret_cast<const f4*>(z + (size_t)row * ROW_D);
    f4* __restrict__ pout      = reinterpret_cast<f4*>(out + (size_t)row * ROW_D);

    // 16 elements/lane, 4 coalesced dwordx4 loads.
    f4 v[4];
#pragma unroll
    for (int j = 0; j < 4; ++j) v[j] = zin[lane + 64 * j];

    // Lane-local top-4 of 16: sort each f4 (4x5 CE), tournament merges.
    float g[4][4];
#pragma unroll
    for (int j = 0; j < 4; ++j) {
        g[j][0] = v[j].x; g[j][1] = v[j].y; g[j][2] = v[j].z; g[j][3] = v[j].w;
        sort4(g[j][0], g[j][1], g[j][2], g[j][3]);
    }
    float a0, a1, a2, a3, b0, b1, b2, b3, T0, T1, T2, T3;
    merge44_top4(g[0][0], g[0][1], g[0][2], g[0][3],
                 g[1][0], g[1][1], g[1][2], g[1][3], a0, a1, a2, a3);
    merge44_top4(g[2][0], g[2][1], g[2][2], g[2][3],
                 g[3][0], g[3][1], g[3][2], g[3][3], b0, b1, b2, b3);
    merge44_top4(a0, a1, a2, a3, b0, b1, b2, b3, T0, T1, T2, T3);

    // Row max = wave max of per-lane maxes (T0).
    const float m = bcast63(dpp_max_to63(T0));
    float t = m - 1.0f;

    // Elements outside a lane's top-4 are <= T3. If T3 <= t0 on every
    // lane, they are <= t for ALL Newton iterates (t only increases) and
    // contribute 0 to S and C forever -> 4-element iterations are EXACT.
    const unsigned long long bad = __ballot(T3 > t);
    if (bad == 0ull) {
        // Fast path: 4 elements/lane/iter.
#pragma unroll 1
        for (int it = 0; it < 16; ++it) {
            const float d0 = T0 - t, d1 = T1 - t, d2 = T2 - t, d3 = T3 - t;
            const float Sl = (fmaxf(d0, 0.0f) + fmaxf(d1, 0.0f)) +
                             (fmaxf(d2, 0.0f) + fmaxf(d3, 0.0f));
            int n = __popcll(__ballot(d0 > 0.0f));     // SALU counts
            n += __popcll(__ballot(d1 > 0.0f));
            n += __popcll(__ballot(d2 > 0.0f));
            n += __popcll(__ballot(d3 > 0.0f));
            const float S = bcast63(dpp_sum_to63(Sl));
            const float step = (S - 1.0f) * fast_rcp((float)n);  // n >= 1
            t += step;
            if (step <= 1e-6f) break;   // wave-uniform exit
        }
    } else {
        // Full path (rare, exact): all 16 elements/lane.
#pragma unroll 1
        for (int it = 0; it < 16; ++it) {
            float sj[4];
            int n = 0;
#pragma unroll
            for (int j = 0; j < 4; ++j) {
                const float d0 = v[j].x - t, d1 = v[j].y - t;
                const float d2 = v[j].z - t, d3 = v[j].w - t;
                sj[j] = (fmaxf(d0, 0.0f) + fmaxf(d1, 0.0f)) +
                        (fmaxf(d2, 0.0f) + fmaxf(d3, 0.0f));
                n += __popcll(__ballot(d0 > 0.0f));
                n += __popcll(__ballot(d1 > 0.0f));
                n += __popcll(__ballot(d2 > 0.0f));
                n += __popcll(__ballot(d3 > 0.0f));
            }
            const float S = bcast63(dpp_sum_to63((sj[0] + sj[1]) + (sj[2] + sj[3])));
            const float step = (S - 1.0f) * fast_rcp((float)n);  // n >= 1
            t += step;
            if (step <= 1e-6f) break;
        }
    }

    // p = relu(z - tau).
#pragma unroll
    for (int j = 0; j < 4; ++j) {
        f4 o;
        o.x = fmaxf(v[j].x - t, 0.0f);
        o.y = fmaxf(v[j].y - t, 0.0f);
        o.z = fmaxf(v[j].z - t, 0.0f);
        o.w = fmaxf(v[j].w - t, 0.0f);
        pout[lane + 64 * j] = o;
    }
}

extern "C" void kernel_launch(void* const* d_in, const int* in_sizes, int n_in,
                              void* d_out, int out_size, void* d_ws, size_t ws_size,
                              hipStream_t stream) {
    const float* z = (const float*)d_in[0];
    float* out = (float*)d_out;
    const int n = in_sizes[0];            // 8*4096*1024
    const int nrows = n / ROW_D;          // 32768
    const int blocks = (nrows + 3) / 4;   // 1 wave per row, 4 waves/block
    sparsemax_kernel<<<blocks, 256, 0, stream>>>(z, out, nrows);
}